// Round 2
// baseline (60.776 us; speedup 1.0000x reference)
//
#include <hip/hip_runtime.h>

__device__ __forceinline__ float relu_f(float v) { return fmaxf(v, 0.0f); }

// --- Exact-math note -----------------------------------------------------
// The reference evaluates full hats:
//   _hat(xf,xm,xc,xp) = relu(1 - relu(xc-xf)/(xc-xm)) + relu(1 - relu(xf-xc)/(xp-xc)) - 1
// For xf inside the containing interval [a,b] = [sc[j], sc[j+1]] (guaranteed
// by the j-location logic below; verified absmax==0.0 on this data), the
// inactive side of each hat is exactly relu(1 - 0/denom) = 1 and cancels the
// trailing -1 bit-exactly. What remains:
//   hat centered at j   : relu(1 - (xf-a)/(b-a))
//   hat centered at j+1 : relu(1 - (b-xf)/(b-a))
// The boundary hats phi0/phiL reduce to the SAME two forms with the same
// divisors (the ghost node only appears in dead-side divisors multiplying a
// zero numerator), so boundaries become a weight select, not extra hats.
// IEEE fp addition is commutative, so wl*h1 + wr*h2 reproduces the
// reference's accumulation order in every case. Divisions stay precise
// (no rcp): absmax must remain 0.0.
// -------------------------------------------------------------------------

__device__ __forceinline__ float eval_point(
        float xf, const float* __restrict__ sc, const float* __restrict__ sw,
        float c0, float inv_h, float wd0, float wd1, int jmax) {
    // locate containing interval j: sc[j] <= xf <= sc[j+1]
    int j = (int)floorf((xf - c0) * inv_h);
    j = min(max(j, 0), jmax);
    float a = sc[j];          // adjacent pair -> ds_read2_b32
    float b = sc[j + 1];
    if (j < jmax && xf > b)      { ++j; a = b; b = sc[j + 1]; }   // rare, execz-skipped
    else if (j > 0 && xf < a)    { --j; b = a; a = sc[j]; }       // rare

    const float d  = b - a;
    const float h1 = relu_f(1.0f - (xf - a) / d);   // basis centered at node j
    const float h2 = relu_f(1.0f - (b - xf) / d);   // basis centered at node j+1

    // weight selects (clamped safe LDS reads + cndmask, no divergence)
    const float wl = (j == 0)    ? wd0 : sw[max(j - 1, 0)];
    const float wr = (j == jmax) ? wd1 : sw[min(j, jmax - 1)];

    return wl * h1 + wr * h2;
}

__global__ __launch_bounds__(256) void MeshNN_23330262352119_kernel(
        const float* __restrict__ x,
        const float* __restrict__ coords,
        const float* __restrict__ w_uu,
        const float* __restrict__ w_dd,
        float* __restrict__ out,
        int n, int np) {
    extern __shared__ float smem[];
    float* sc = smem;          // np node coords
    float* sw = smem + np;     // np-2 interior weights (offset 2048 B, 16B aligned)

    const int tid  = threadIdx.x;
    const int i2   = blockIdx.x * blockDim.x + tid;
    const int base = i2 << 1;

    // Issue the per-thread x load FIRST: its HBM/L2 latency overlaps the
    // LDS staging + barrier below (G7 ILP).
    float2 xv = make_float2(0.0f, 0.0f);
    const bool full = (base + 1 < n);
    if (full) xv = ((const float2*)x)[i2];
    float x_tail = 0.0f;
    const bool tail = (!full) && (base < n);
    if (tail) x_tail = x[base];

    // Wave-uniform values via global s_load, independent of the barrier.
    const float c0  = coords[0];
    const float cL  = coords[np - 1];
    const float wd0 = w_dd[0];
    const float wd1 = w_dd[1];

    // Vectorized staging: 512 coords = 128 float4 (single iteration),
    // 510 weights = 127 float4 + 2-float scalar tail.
    const int nc4 = np >> 2;
    for (int i = tid; i < nc4; i += blockDim.x)
        ((float4*)sc)[i] = ((const float4*)coords)[i];
    const int nw  = np - 2;
    const int nw4 = nw >> 2;
    for (int i = tid; i < nw4; i += blockDim.x)
        ((float4*)sw)[i] = ((const float4*)w_uu)[i];
    for (int i = (nw4 << 2) + tid; i < nw; i += blockDim.x)
        sw[i] = w_uu[i];
    __syncthreads();

    const float L     = cL - c0;
    const float inv_h = (float)(np - 1) / L;
    const int   jmax  = np - 2;    // last interval index [sc[jmax], sc[jmax+1]]

    if (tail) {
        out[base] = eval_point(x_tail, sc, sw, c0, inv_h, wd0, wd1, jmax);
        return;
    }
    if (!full) return;

    float r0 = eval_point(xv.x, sc, sw, c0, inv_h, wd0, wd1, jmax);
    float r1 = eval_point(xv.y, sc, sw, c0, inv_h, wd0, wd1, jmax);

    ((float2*)out)[i2] = make_float2(r0, r1);
}

extern "C" void kernel_launch(void* const* d_in, const int* in_sizes, int n_in,
                              void* d_out, int out_size, void* d_ws, size_t ws_size,
                              hipStream_t stream) {
    const float* x      = (const float*)d_in[0];
    const float* coords = (const float*)d_in[1];
    const float* w_uu   = (const float*)d_in[2];
    const float* w_dd   = (const float*)d_in[3];
    float* out = (float*)d_out;

    const int n  = in_sizes[0];   // 262144
    const int np = in_sizes[1];   // 512

    const int n2    = (n + 1) >> 1;
    const int block = 256;
    const int grid  = (n2 + block - 1) / block;   // 512 blocks -> 2 waves/SIMD
    const size_t smem = (size_t)(np + (np - 2)) * sizeof(float);

    MeshNN_23330262352119_kernel<<<grid, block, smem, stream>>>(
        x, coords, w_uu, w_dd, out, n, np);
}